// Round 3
// baseline (760.772 us; speedup 1.0000x reference)
//
#include <hip/hip_runtime.h>
#include <stdint.h>

// ===== LinearQ4_0: out[8192,11008] = x[8192,4096] * W^T, W q4_0 packed =====
#define IN_F   4096
#define OUT_F  11008
#define M_ROWS 8192
#define BM 256
#define BN 256
#define BK 64
#define NTILE_K (IN_F / BK)   // 64

typedef __attribute__((ext_vector_type(4))) float  f32x4;
typedef __attribute__((ext_vector_type(4))) int    int4v;
typedef __attribute__((ext_vector_type(8))) unsigned short ushort8;
typedef __bf16 bf16x8 __attribute__((ext_vector_type(8)));

__device__ __forceinline__ unsigned short f2bf(float f) {
  unsigned int u = __builtin_bit_cast(unsigned int, f);
  u += 0x7fffu + ((u >> 16) & 1u);
  return (unsigned short)(u >> 16);
}

// ---- kernel 1: dequantize q4_0 -> bf16 W[OUT_F][IN_F] ----
__global__ __launch_bounds__(256) void dequant_q40(const int* __restrict__ w,
                                                   const float* __restrict__ sc,
                                                   unsigned short* __restrict__ wb) {
  const int total8 = (OUT_F * IN_F) / 8;
  for (int t = blockIdx.x * blockDim.x + threadIdx.x; t < total8;
       t += gridDim.x * blockDim.x) {
    const int f0  = t * 8;
    const int p   = f0 >> 7;
    const int nib = (f0 >> 6) & 1;
    const int j0  = f0 & 63;
    const float scale = sc[f0 >> 6];
    const int* src = w + p * 64 + j0;
    const int4v b0 = *reinterpret_cast<const int4v*>(src);
    const int4v b1 = *reinterpret_cast<const int4v*>(src + 4);
    ushort8 r;
#pragma unroll
    for (int e = 0; e < 4; ++e) {
      const int v0 = b0[e], v1 = b1[e];
      const int q0 = nib ? ((v0 << 28) >> 28) : (v0 >> 4);
      const int q1 = nib ? ((v1 << 28) >> 28) : (v1 >> 4);
      r[e]     = f2bf((float)q0 * scale);
      r[4 + e] = f2bf((float)q1 * scale);
    }
    *reinterpret_cast<ushort8*>(wb + f0) = r;
  }
}

// ---- kernel 2: x fp32 -> bf16 ----
__global__ __launch_bounds__(256) void cvt_x(const float* __restrict__ x,
                                             unsigned short* __restrict__ xb) {
  const int total8 = (M_ROWS * IN_F) / 8;
  for (int t = blockIdx.x * blockDim.x + threadIdx.x; t < total8;
       t += gridDim.x * blockDim.x) {
    const f32x4 a0 = *reinterpret_cast<const f32x4*>(x + t * 8);
    const f32x4 a1 = *reinterpret_cast<const f32x4*>(x + t * 8 + 4);
    ushort8 r;
#pragma unroll
    for (int e = 0; e < 4; ++e) {
      r[e]     = f2bf(a0[e]);
      r[4 + e] = f2bf(a1[e]);
    }
    *reinterpret_cast<ushort8*>(xb + t * 8) = r;
  }
}

// ---- async global -> LDS, 16 B per lane ----
__device__ __forceinline__ void gld16(const void* g, void* l) {
  __builtin_amdgcn_global_load_lds(
      (const __attribute__((address_space(1))) unsigned int*)(uintptr_t)g,
      (__attribute__((address_space(3))) unsigned int*)(unsigned int)(uintptr_t)l,
      16, 0, 0);
}

#define BARRIER() do { asm volatile("" ::: "memory"); __builtin_amdgcn_s_barrier(); \
                       asm volatile("" ::: "memory"); } while (0)
#define SCHEDB()  __builtin_amdgcn_sched_barrier(0)

// ---- kernel 3: 256x256 tile, BK=64, 8 waves, pipelined 4-phase schedule ----
// Phase Qi-top reads NEXT phase's A-subtile (alternating reg sets); B reloaded for
// tile t+1 inside Q3's MFMA segment. Counted vmcnt(6)/vmcnt(2), never 0 in loop.
// LDS swizzle: phys 16B-chunk = logical ^ (row&7) (involution; linear gld dest +
// inverse-swizzled global source + same XOR on ds_read).
__global__ __launch_bounds__(512, 2) void gemm_bt(const unsigned short* __restrict__ A,
                                                  const unsigned short* __restrict__ B,
                                                  float* __restrict__ C) {
  __shared__ __align__(16) unsigned short lds[65536];  // 128 KB, 2 buffers

  const int NT  = OUT_F / BN;              // 43
  const int nwg = (M_ROWS / BM) * NT;      // 1376, %8==0
  const int cpx = nwg >> 3;
  const int bid = blockIdx.x;
  const int swz = (bid & 7) * cpx + (bid >> 3);
  const int mt  = swz / NT;
  const int nt  = swz - mt * NT;

  const int tid  = threadIdx.x;
  const int lane = tid & 63;
  const int wid  = tid >> 6;      // 8 waves: 2 (M) x 4 (N)
  const int wr   = wid >> 2;      // 0..1 -> 128 rows
  const int wc   = wid & 3;       // 0..3 -> 64 cols

  // ---- staging: linear LDS dest, pre-swizzled global source ----
  const int p_row   = tid >> 3;
  const int l_chunk = (tid & 7) ^ (p_row & 7);
  const unsigned short* gA = A + (size_t)(mt * BM + p_row) * IN_F + l_chunk * 8;
  const unsigned short* gB = B + (size_t)(nt * BM + p_row) * IN_F + l_chunk * 8;
  unsigned short* ldsw = lds + tid * 8;

#define STAGE_A(p, c, kk) gld16(gA + (size_t)(64 * (c)) * IN_F + (kk), \
                                ldsw + (p) * 32768 + (c) * 4096)
#define STAGE_B(p, c, kk) gld16(gB + (size_t)(64 * (c)) * IN_F + (kk), \
                                ldsw + (p) * 32768 + 16384 + (c) * 4096)

  // ---- fragment read addressing (swizzled; row&7 == fr&7 for all our rows) ----
  const int fr   = lane & 15;
  const int kq   = lane >> 4;
  const int axor = lane & 7;
  const int c0   = ((kq) ^ axor) * 8;
  const int c1   = ((4 + kq) ^ axor) * 8;
#define RDF(base, row, cs) (*reinterpret_cast<const bf16x8*>((base) + (size_t)(row) * 64 + (cs)))

#define RD_A(dst, buf, mq) do {                                          \
    _Pragma("unroll") for (int mm = 0; mm < 2; ++mm) {                   \
      const int r_ = wr * 128 + (mq) * 32 + mm * 16 + fr;                \
      dst[mm][0] = RDF(buf, r_, c0); dst[mm][1] = RDF(buf, r_, c1);      \
    } } while (0)

  f32x4 acc[8][4] = {};
  bf16x8 sA[2][2], sBst[2][2], b[4][2];

#define MFMA_SEG(mi, aset) do {                                                    \
    __builtin_amdgcn_s_setprio(1);                                                 \
    _Pragma("unroll") for (int mm = 0; mm < 2; ++mm)                               \
      _Pragma("unroll") for (int nn = 0; nn < 4; ++nn) {                           \
        acc[(mi)*2+mm][nn] = __builtin_amdgcn_mfma_f32_16x16x32_bf16(              \
            aset[mm][0], b[nn][0], acc[(mi)*2+mm][nn], 0, 0, 0);                   \
        acc[(mi)*2+mm][nn] = __builtin_amdgcn_mfma_f32_16x16x32_bf16(              \
            aset[mm][1], b[nn][1], acc[(mi)*2+mm][nn], 0, 0, 0);                   \
      }                                                                            \
    __builtin_amdgcn_s_setprio(0);                                                 \
  } while (0)

  // ---- prologue: stage tile0 into buf0, drain, read B(0)+A0(0) ----
  STAGE_A(0, 0, 0); STAGE_A(0, 1, 0); STAGE_A(0, 2, 0); STAGE_A(0, 3, 0);
  STAGE_B(0, 0, 0); STAGE_B(0, 1, 0); STAGE_B(0, 2, 0); STAGE_B(0, 3, 0);
  asm volatile("s_waitcnt vmcnt(0)" ::: "memory");
  __builtin_amdgcn_s_barrier();
  asm volatile("" ::: "memory");
  {
    const unsigned short* bufB0 = lds + 16384;
#pragma unroll
    for (int nn = 0; nn < 4; ++nn) {
      const int rb = wc * 64 + nn * 16 + fr;
      b[nn][0] = RDF(bufB0, rb, c0); b[nn][1] = RDF(bufB0, rb, c1);
    }
    RD_A(sA, lds, 0);
  }

  for (int t = 0; t < NTILE_K; ++t) {
    const int p = t & 1, q = p ^ 1;
    const unsigned short* bufAp = lds + p * 32768;
    const unsigned short* bufAq = lds + q * 32768;
    const unsigned short* bufBq = bufAq + 16384;
    const int k1 = (t + 1 < NTILE_K ? t + 1 : 0) * BK;

    // ---- Q0: top{read A1(t)->sBst; stage [B x4, Ar0, Ar2](t+1)} ----
    RD_A(sBst, bufAp, 1);
    STAGE_B(q, 0, k1); STAGE_B(q, 1, k1); STAGE_B(q, 2, k1); STAGE_B(q, 3, k1);
    STAGE_A(q, 0, k1); STAGE_A(q, 2, k1);
    BARRIER(); SCHEDB();
    MFMA_SEG(0, sA);
    SCHEDB();
    asm volatile("s_waitcnt vmcnt(6)" ::: "memory");  // Ar1(t),Ar3(t) resident
    BARRIER();

    // ---- Q1: top{read A2(t)->sA; stage Ar1(t+1)} ----
    RD_A(sA, bufAp, 2);
    STAGE_A(q, 1, k1);
    BARRIER(); SCHEDB();
    MFMA_SEG(1, sBst);
    SCHEDB();
    BARRIER();

    // ---- Q2: top{read A3(t)->sBst; stage Ar3(t+1)} ----
    RD_A(sBst, bufAp, 3);
    STAGE_A(q, 3, k1);
    BARRIER(); SCHEDB();
    MFMA_SEG(2, sA);
    SCHEDB();
    asm volatile("s_waitcnt vmcnt(2)" ::: "memory");  // [B,Ar0,Ar2](t+1) resident
    BARRIER();

    // ---- Q3: top{read A0(t+1)->sA from buf q}; MFMA w/ interleaved B(t+1) reload ----
    RD_A(sA, bufAq, 0);
    BARRIER(); SCHEDB();
    __builtin_amdgcn_s_setprio(1);
#pragma unroll
    for (int nn = 0; nn < 4; ++nn) {
      acc[6][nn] = __builtin_amdgcn_mfma_f32_16x16x32_bf16(sBst[0][0], b[nn][0], acc[6][nn], 0, 0, 0);
      acc[6][nn] = __builtin_amdgcn_mfma_f32_16x16x32_bf16(sBst[0][1], b[nn][1], acc[6][nn], 0, 0, 0);
      acc[7][nn] = __builtin_amdgcn_mfma_f32_16x16x32_bf16(sBst[1][0], b[nn][0], acc[7][nn], 0, 0, 0);
      acc[7][nn] = __builtin_amdgcn_mfma_f32_16x16x32_bf16(sBst[1][1], b[nn][1], acc[7][nn], 0, 0, 0);
      const int rb = wc * 64 + nn * 16 + fr;   // b[nn] free now: reload for t+1
      b[nn][0] = RDF(bufBq, rb, c0);
      b[nn][1] = RDF(bufBq, rb, c1);
    }
    __builtin_amdgcn_s_setprio(0);
    SCHEDB();
    BARRIER();
  }

  // ---- epilogue: C write. acc[m][n]: row = wr*128 + m*16 + (lane>>4)*4 + r, col = wc*64 + n*16 + fr ----
  const int col  = nt * BN + wc * 64 + fr;
  const int row0 = mt * BM + wr * 128 + (lane >> 4) * 4;
#pragma unroll
  for (int m = 0; m < 8; ++m) {
#pragma unroll
    for (int n = 0; n < 4; ++n) {
      float* cp = C + (size_t)(row0 + m * 16) * OUT_F + (col + n * 16);
#pragma unroll
      for (int r = 0; r < 4; ++r) cp[(size_t)r * OUT_F] = acc[m][n][r];
    }
  }
}

extern "C" void kernel_launch(void* const* d_in, const int* in_sizes, int n_in,
                              void* d_out, int out_size, void* d_ws, size_t ws_size,
                              hipStream_t stream) {
  const float* x = (const float*)d_in[0];
  const int*   w = (const int*)d_in[1];
  const float* s = (const float*)d_in[2];
  float*     out = (float*)d_out;

  unsigned short* wb = (unsigned short*)d_ws;             // bf16 W  [OUT_F][IN_F]
  unsigned short* xb = wb + (size_t)OUT_F * IN_F;         // bf16 x  [M_ROWS][IN_F]

  dequant_q40<<<dim3(2048), dim3(256), 0, stream>>>(w, s, wb);
  cvt_x<<<dim3(2048), dim3(256), 0, stream>>>(x, xb);
  gemm_bt<<<dim3((M_ROWS / BM) * (OUT_F / BN)), dim3(512), 0, stream>>>(xb, wb, out);
}